// Round 13
// baseline (202.041 us; speedup 1.0000x reference)
//
#include <hip/hip_runtime.h>

constexpr int NB  = 64;
constexpr int NI  = 512;
constexpr int STK = 6000;
constexpr int EMB = 16;
constexpr int CAP = 64;     // max uses per id (Poisson mean 5.46; validated no drops)
constexpr int ROWP = 20;    // padded LDS row stride (floats)

typedef __attribute__((ext_vector_type(8))) unsigned short ushort8;

static __device__ __forceinline__ unsigned short f2bf_rn(float x) {
    unsigned u = __float_as_uint(x);
    unsigned r = (u + 0x7FFFu + ((u >> 16) & 1u)) >> 16;   // round-to-nearest-even
    return (unsigned short)r;
}
static __device__ __forceinline__ float bf2f(unsigned short h) {
    return __uint_as_float((unsigned)h << 16);
}

// ---------- pass 1: batch-structured. P' = p*att (bf16, diag 0); fused scatter.
// R13: 64-i tile (512 blocks, staging total unchanged) but 8 waves/block ->
// 16 waves/CU. i-group shrunk 4->2 to keep VGPR <=128 (4 waves/SIMD).
constexpr int T1 = 512;
__global__ __launch_bounds__(T1, 4)
void pass1_att(const float* __restrict__ prices,
               const float* __restrict__ emb_table,
               const int* __restrict__ stock_ids,
               unsigned short* __restrict__ Pp,
               int* __restrict__ counts,
               int* __restrict__ list,
               unsigned short* __restrict__ sid16) {
    __shared__ float semb[NI][ROWP];       // 40960 B; 2 blocks/CU resident
    const int b = blockIdx.x, tile = blockIdx.y, tid = threadIdx.x;
    const int lane = tid & 63, wave = tid >> 6;

    // Stage: lane -> (row, quarter): each wave-inst touches 16 lines.
    for (int t = tid; t < NI * 4; t += T1) {
        const int r = t >> 2, q = t & 3;
        const int sid = stock_ids[b * NI + r];
        ((float4*)&semb[r][0])[q] =
            ((const float4*)(emb_table + (long long)sid * EMB))[q];
    }

    // Fused scatter + sid16 pack: this block owns i = tile*64 .. +63 of batch b.
    if (tid < 64) {
        const int idx = b * NI + tile * 64 + tid;
        const int s = stock_ids[idx];
        sid16[idx] = (unsigned short)s;
        const int pos = atomicAdd(&counts[s], 1);
        if (pos < CAP) list[s * CAP + pos] = idx;
    }
    __syncthreads();

    const int i0 = tile * 64 + wave * 8;   // each wave: 8 i's, 4 groups of 2
    #pragma unroll
    for (int g = 0; g < 4; ++g) {
        const int ia = i0 + g * 2;
        float ei[2][16];
        #pragma unroll
        for (int m = 0; m < 2; ++m) {
            #pragma unroll
            for (int q = 0; q < 4; ++q) {
                float4 v = ((const float4*)(&semb[ia + m][0]))[q];
                ei[m][4*q+0] = v.x; ei[m][4*q+1] = v.y;
                ei[m][4*q+2] = v.z; ei[m][4*q+3] = v.w;
            }
        }

        float ex[2][8];
        float denom[2] = {0.f, 0.f};
        #pragma unroll
        for (int k = 0; k < 8; ++k) {
            const int j = lane + 64 * k;
            const float4* e4 = (const float4*)(&semb[j][0]);
            const float4 a0 = e4[0], a1 = e4[1], a2 = e4[2], a3 = e4[3];
            #pragma unroll
            for (int m = 0; m < 2; ++m) {
                const float* e = ei[m];
                float d = ((e[0]*a0.x + e[1]*a0.y) + (e[2]*a0.z + e[3]*a0.w))
                        + ((e[4]*a1.x + e[5]*a1.y) + (e[6]*a1.z + e[7]*a1.w))
                        + ((e[8]*a2.x + e[9]*a2.y) + (e[10]*a2.z + e[11]*a2.w))
                        + ((e[12]*a3.x + e[13]*a3.y) + (e[14]*a3.z + e[15]*a3.w));
                float exv = __expf(d);
                if (j == ia + m) exv = 0.f;          // diag: exp(-inf) = 0
                ex[m][k] = exv;
                denom[m] += exv;
            }
        }

        #pragma unroll
        for (int m = 0; m < 2; ++m) {
            float dsum = denom[m];
            #pragma unroll
            for (int off = 32; off; off >>= 1) dsum += __shfl_xor(dsum, off);
            const int i = ia + m;
            const float p = prices[b * NI + i];
            const float scale = p / (dsum + 1e-8f);
            unsigned short* dst = Pp + (size_t)(b * NI + i) * NI;
            #pragma unroll
            for (int k = 0; k < 8; ++k)
                dst[k * 64 + lane] = f2bf_rn(ex[m][k] * scale);
        }
    }
}

// ---------- pass 2: 1 id per block (R7 proven, ~29 us) ----------
constexpr int T2 = 512;
__global__ __launch_bounds__(T2)
void pass2_beta(const float* __restrict__ prices,
                const float* __restrict__ beta,
                const unsigned short* __restrict__ sid16,
                const int* __restrict__ counts,
                const int* __restrict__ list,
                const unsigned short* __restrict__ Pp,
                float* __restrict__ out) {
    __shared__ float row[STK];          // 24000 B
    const int s = blockIdx.x;
    const int cnt0 = counts[s];
    if (cnt0 == 0) return;              // uniform exit before any barrier
    const int cnt = cnt0 < CAP ? cnt0 : CAP;
    const int tid = threadIdx.x, lane = tid & 63, wave = tid >> 6;

    const float4* src4 = (const float4*)(beta + (long long)s * STK);
    float4* dst4 = (float4*)row;
    for (int t = tid; t < STK / 4; t += T2) dst4[t] = src4[t];
    __syncthreads();

    for (int u = wave; u < cnt; u += T2 / 64) {
        const int idx = list[s * CAP + u];
        const int b = idx >> 9;
        const unsigned short* __restrict__ Prow = Pp + (size_t)idx * NI;
        const unsigned short* __restrict__ sidb = sid16 + b * NI;

        const int j0 = lane * 8;
        const ushort8 pv = *(const ushort8*)(Prow + j0);
        const ushort8 sj = *(const ushort8*)(sidb + j0);

        float v = 0.f;
        #pragma unroll
        for (int e = 0; e < 8; ++e) {
            const int sje = (int)sj[e];
            v += (sje == s) ? 0.f : bf2f(pv[e]) * row[sje];
        }

        #pragma unroll
        for (int off = 32; off; off >>= 1) v += __shfl_xor(v, off);

        if (lane == 0) {
            const float p = prices[idx];
            out[idx] = v;                   // virtual
            out[NB * NI + idx] = v - p;     // u
        }
    }
}

// ---------- fallback: proven single-kernel version ----------
constexpr int TILE_I = 64;
constexpr int FB_THREADS = 256;

__global__ __launch_bounds__(FB_THREADS)
void stock_factor_fallback(const float* __restrict__ prices,
                           const float* __restrict__ emb_table,
                           const float* __restrict__ beta,
                           const int* __restrict__ stock_ids,
                           float* __restrict__ out) {
    __shared__ float semb[NI][ROWP];
    __shared__ int   ssid[NI];
    const int b = blockIdx.x, tile = blockIdx.y, tid = threadIdx.x;
    const int lane = tid & 63, wave = tid >> 6;
    for (int r = tid; r < NI; r += FB_THREADS) {
        const int sid = stock_ids[b * NI + r];
        ssid[r] = sid;
        const float4* src = (const float4*)(emb_table + (long long)sid * 16);
        float4 v0 = src[0], v1 = src[1], v2 = src[2], v3 = src[3];
        float4* dst = (float4*)(&semb[r][0]);
        dst[0] = v0; dst[1] = v1; dst[2] = v2; dst[3] = v3;
    }
    __syncthreads();
    const int i0 = tile * TILE_I + wave * (TILE_I / 4);
    for (int ii = 0; ii < TILE_I / 4; ++ii) {
        const int i = i0 + ii;
        const int sid_i = ssid[i];
        const float* __restrict__ brow = beta + (long long)sid_i * STK;
        float ei[16];
        #pragma unroll
        for (int q = 0; q < 4; ++q) {
            float4 v = ((const float4*)(&semb[i][0]))[q];
            ei[4*q+0]=v.x; ei[4*q+1]=v.y; ei[4*q+2]=v.z; ei[4*q+3]=v.w;
        }
        float denom = 0.f, numer = 0.f;
        #pragma unroll
        for (int k = 0; k < 8; ++k) {
            const int j = lane + 64 * k;
            const float4* ej4 = (const float4*)(&semb[j][0]);
            const float4 a0 = ej4[0], a1 = ej4[1], a2 = ej4[2], a3 = ej4[3];
            const int sid_j = ssid[j];
            const float bv = brow[sid_j];
            float d;
            d  = ei[0]*a0.x;  d += ei[1]*a0.y;  d += ei[2]*a0.z;  d += ei[3]*a0.w;
            d += ei[4]*a1.x;  d += ei[5]*a1.y;  d += ei[6]*a1.z;  d += ei[7]*a1.w;
            d += ei[8]*a2.x;  d += ei[9]*a2.y;  d += ei[10]*a2.z; d += ei[11]*a2.w;
            d += ei[12]*a3.x; d += ei[13]*a3.y; d += ei[14]*a3.z; d += ei[15]*a3.w;
            float ex = __expf(d);
            if (j == i) ex = 0.f;
            denom += ex;
            numer += (sid_j == sid_i) ? 0.f : ex * bv;
        }
        #pragma unroll
        for (int off = 32; off; off >>= 1) {
            denom += __shfl_xor(denom, off);
            numer += __shfl_xor(numer, off);
        }
        if (lane == 0) {
            const float p = prices[b * NI + i];
            const float v = p * numer / (denom + 1e-8f);
            out[b * NI + i] = v;
            out[NB * NI + b * NI + i] = v - p;
        }
    }
}

extern "C" void kernel_launch(void* const* d_in, const int* in_sizes, int n_in,
                              void* d_out, int out_size, void* d_ws, size_t ws_size,
                              hipStream_t stream) {
    const float* prices    = (const float*)d_in[0];
    const float* emb_table = (const float*)d_in[1];
    const float* beta      = (const float*)d_in[2];
    const int*   stock_ids = (const int*)d_in[3];
    float* out = (float*)d_out;

    const size_t pp_bytes   = (size_t)NB * NI * NI * sizeof(unsigned short); // 32 MiB
    const size_t counts_off = pp_bytes;
    const size_t list_off   = counts_off + (size_t)STK * sizeof(int);
    const size_t sid16_off  = list_off + (size_t)STK * CAP * sizeof(int);
    const size_t need       = sid16_off + (size_t)NB * NI * sizeof(unsigned short);

    if (ws_size >= need) {
        unsigned short* Pp    = (unsigned short*)d_ws;
        int* counts           = (int*)((char*)d_ws + counts_off);
        int* list             = (int*)((char*)d_ws + list_off);
        unsigned short* sid16 = (unsigned short*)((char*)d_ws + sid16_off);
        hipMemsetAsync(counts, 0, (size_t)STK * sizeof(int), stream);
        pass1_att<<<dim3(NB, NI / 64), T1, 0, stream>>>(prices, emb_table, stock_ids,
                                                        Pp, counts, list, sid16);
        pass2_beta<<<STK, T2, 0, stream>>>(prices, beta, sid16, counts, list,
                                           Pp, out);
    } else {
        dim3 grid(NB, NI / TILE_I);
        stock_factor_fallback<<<grid, FB_THREADS, 0, stream>>>(
            prices, emb_table, beta, stock_ids, out);
    }
}

// Round 14
// 60.831 us; speedup vs baseline: 3.3214x; 3.3214x over previous
//
#include <hip/hip_runtime.h>

constexpr int NB  = 64;
constexpr int NI  = 512;
constexpr int STK = 6000;
constexpr int EMB = 16;
constexpr int CAP = 64;     // max uses per id (Poisson mean 5.46; validated no drops)
constexpr int ROWP = 20;    // padded LDS row stride (floats)

typedef __attribute__((ext_vector_type(8))) unsigned short ushort8;

static __device__ __forceinline__ unsigned short f2bf_rn(float x) {
    unsigned u = __float_as_uint(x);
    unsigned r = (u + 0x7FFFu + ((u >> 16) & 1u)) >> 16;   // round-to-nearest-even
    return (unsigned short)r;
}
static __device__ __forceinline__ float bf2f(unsigned short h) {
    return __uint_as_float((unsigned)h << 16);
}

// ---------- pass 1: batch-structured. Stores UNSCALED exp(d) in bf16 (diag 0)
// immediately (no ex[] stash -> low VGPR), plus per-i scale = p/(denom+eps).
// T1=512, grid 512 -> 16 waves/CU. ----------
constexpr int T1 = 512;
__global__ __launch_bounds__(T1, 4)    // 4 waves/EU -> VGPR <= 128 (core needs ~100)
void pass1_att(const float* __restrict__ prices,
               const float* __restrict__ emb_table,
               const int* __restrict__ stock_ids,
               unsigned short* __restrict__ Pp,
               int* __restrict__ counts,
               int* __restrict__ list,
               unsigned short* __restrict__ sid16,
               float* __restrict__ scale) {
    __shared__ float semb[NI][ROWP];       // 40960 B
    const int b = blockIdx.x, tile = blockIdx.y, tid = threadIdx.x;
    const int lane = tid & 63, wave = tid >> 6;

    // Stage 512 emb rows; 4 threads/row -> 16 distinct lines per wave-inst.
    for (int t = tid; t < NI * 4; t += T1) {
        const int r = t >> 2, q = t & 3;
        const int sid = stock_ids[b * NI + r];
        ((float4*)&semb[r][0])[q] =
            ((const float4*)(emb_table + (long long)sid * EMB))[q];
    }

    // Fused scatter + sid16 pack: block owns i = tile*64 .. +63 of batch b.
    if (tid < 64) {
        const int idx = b * NI + tile * 64 + tid;
        const int s = stock_ids[idx];
        sid16[idx] = (unsigned short)s;
        const int pos = atomicAdd(&counts[s], 1);
        if (pos < CAP) list[s * CAP + pos] = idx;
    }
    __syncthreads();

    const int i0 = tile * 64 + wave * 8;   // each wave: 8 i's, 2 groups of 4
    #pragma unroll
    for (int g = 0; g < 2; ++g) {
        const int ia = i0 + g * 4;
        float ei[4][16];
        unsigned short* dst[4];
        #pragma unroll
        for (int m = 0; m < 4; ++m) {
            #pragma unroll
            for (int q = 0; q < 4; ++q) {
                float4 v = ((const float4*)(&semb[ia + m][0]))[q];
                ei[m][4*q+0] = v.x; ei[m][4*q+1] = v.y;
                ei[m][4*q+2] = v.z; ei[m][4*q+3] = v.w;
            }
            dst[m] = Pp + (size_t)(b * NI + ia + m) * NI + lane;
        }

        float denom[4] = {0.f, 0.f, 0.f, 0.f};
        #pragma unroll
        for (int k = 0; k < 8; ++k) {
            const int j = lane + 64 * k;
            const float4* e4 = (const float4*)(&semb[j][0]);
            const float4 a0 = e4[0], a1 = e4[1], a2 = e4[2], a3 = e4[3];
            #pragma unroll
            for (int m = 0; m < 4; ++m) {
                const float* e = ei[m];
                float d = ((e[0]*a0.x + e[1]*a0.y) + (e[2]*a0.z + e[3]*a0.w))
                        + ((e[4]*a1.x + e[5]*a1.y) + (e[6]*a1.z + e[7]*a1.w))
                        + ((e[8]*a2.x + e[9]*a2.y) + (e[10]*a2.z + e[11]*a2.w))
                        + ((e[12]*a3.x + e[13]*a3.y) + (e[14]*a3.z + e[15]*a3.w));
                float exv = __expf(d);
                if (j == ia + m) exv = 0.f;          // diag: exp(-inf) = 0
                denom[m] += exv;
                dst[m][k * 64] = f2bf_rn(exv);       // store NOW (unscaled)
            }
        }

        #pragma unroll
        for (int m = 0; m < 4; ++m) {
            float dsum = denom[m];
            #pragma unroll
            for (int off = 32; off; off >>= 1) dsum += __shfl_xor(dsum, off);
            if (lane == 0) {
                const int i = ia + m;
                scale[b * NI + i] = prices[b * NI + i] / (dsum + 1e-8f);
            }
        }
    }
}

// ---------- pass 2: 1 id per block (R7 proven); applies deferred scale ----------
constexpr int T2 = 512;
__global__ __launch_bounds__(T2)
void pass2_beta(const float* __restrict__ prices,
                const float* __restrict__ beta,
                const unsigned short* __restrict__ sid16,
                const int* __restrict__ counts,
                const int* __restrict__ list,
                const unsigned short* __restrict__ Pp,
                const float* __restrict__ scale,
                float* __restrict__ out) {
    __shared__ float row[STK];          // 24000 B
    const int s = blockIdx.x;
    const int cnt0 = counts[s];
    if (cnt0 == 0) return;              // uniform exit before any barrier
    const int cnt = cnt0 < CAP ? cnt0 : CAP;
    const int tid = threadIdx.x, lane = tid & 63, wave = tid >> 6;

    const float4* src4 = (const float4*)(beta + (long long)s * STK);
    float4* dst4 = (float4*)row;
    for (int t = tid; t < STK / 4; t += T2) dst4[t] = src4[t];
    __syncthreads();

    for (int u = wave; u < cnt; u += T2 / 64) {
        const int idx = list[s * CAP + u];
        const int b = idx >> 9;
        const unsigned short* __restrict__ Prow = Pp + (size_t)idx * NI;
        const unsigned short* __restrict__ sidb = sid16 + b * NI;

        const int j0 = lane * 8;
        const ushort8 pv = *(const ushort8*)(Prow + j0);
        const ushort8 sj = *(const ushort8*)(sidb + j0);

        float v = 0.f;
        #pragma unroll
        for (int e = 0; e < 8; ++e) {
            const int sje = (int)sj[e];
            v += (sje == s) ? 0.f : bf2f(pv[e]) * row[sje];
        }

        #pragma unroll
        for (int off = 32; off; off >>= 1) v += __shfl_xor(v, off);

        if (lane == 0) {
            const float p = prices[idx];
            const float vf = v * scale[idx];    // deferred p/(denom+eps)
            out[idx] = vf;                      // virtual
            out[NB * NI + idx] = vf - p;        // u
        }
    }
}

// ---------- fallback: proven single-kernel version ----------
constexpr int TILE_I = 64;
constexpr int FB_THREADS = 256;

__global__ __launch_bounds__(FB_THREADS)
void stock_factor_fallback(const float* __restrict__ prices,
                           const float* __restrict__ emb_table,
                           const float* __restrict__ beta,
                           const int* __restrict__ stock_ids,
                           float* __restrict__ out) {
    __shared__ float semb[NI][ROWP];
    __shared__ int   ssid[NI];
    const int b = blockIdx.x, tile = blockIdx.y, tid = threadIdx.x;
    const int lane = tid & 63, wave = tid >> 6;
    for (int r = tid; r < NI; r += FB_THREADS) {
        const int sid = stock_ids[b * NI + r];
        ssid[r] = sid;
        const float4* src = (const float4*)(emb_table + (long long)sid * 16);
        float4 v0 = src[0], v1 = src[1], v2 = src[2], v3 = src[3];
        float4* dst = (float4*)(&semb[r][0]);
        dst[0] = v0; dst[1] = v1; dst[2] = v2; dst[3] = v3;
    }
    __syncthreads();
    const int i0 = tile * TILE_I + wave * (TILE_I / 4);
    for (int ii = 0; ii < TILE_I / 4; ++ii) {
        const int i = i0 + ii;
        const int sid_i = ssid[i];
        const float* __restrict__ brow = beta + (long long)sid_i * STK;
        float ei[16];
        #pragma unroll
        for (int q = 0; q < 4; ++q) {
            float4 v = ((const float4*)(&semb[i][0]))[q];
            ei[4*q+0]=v.x; ei[4*q+1]=v.y; ei[4*q+2]=v.z; ei[4*q+3]=v.w;
        }
        float denom = 0.f, numer = 0.f;
        #pragma unroll
        for (int k = 0; k < 8; ++k) {
            const int j = lane + 64 * k;
            const float4* ej4 = (const float4*)(&semb[j][0]);
            const float4 a0 = ej4[0], a1 = ej4[1], a2 = ej4[2], a3 = ej4[3];
            const int sid_j = ssid[j];
            const float bv = brow[sid_j];
            float d;
            d  = ei[0]*a0.x;  d += ei[1]*a0.y;  d += ei[2]*a0.z;  d += ei[3]*a0.w;
            d += ei[4]*a1.x;  d += ei[5]*a1.y;  d += ei[6]*a1.z;  d += ei[7]*a1.w;
            d += ei[8]*a2.x;  d += ei[9]*a2.y;  d += ei[10]*a2.z; d += ei[11]*a2.w;
            d += ei[12]*a3.x; d += ei[13]*a3.y; d += ei[14]*a3.z; d += ei[15]*a3.w;
            float ex = __expf(d);
            if (j == i) ex = 0.f;
            denom += ex;
            numer += (sid_j == sid_i) ? 0.f : ex * bv;
        }
        #pragma unroll
        for (int off = 32; off; off >>= 1) {
            denom += __shfl_xor(denom, off);
            numer += __shfl_xor(numer, off);
        }
        if (lane == 0) {
            const float p = prices[b * NI + i];
            const float v = p * numer / (denom + 1e-8f);
            out[b * NI + i] = v;
            out[NB * NI + b * NI + i] = v - p;
        }
    }
}

extern "C" void kernel_launch(void* const* d_in, const int* in_sizes, int n_in,
                              void* d_out, int out_size, void* d_ws, size_t ws_size,
                              hipStream_t stream) {
    const float* prices    = (const float*)d_in[0];
    const float* emb_table = (const float*)d_in[1];
    const float* beta      = (const float*)d_in[2];
    const int*   stock_ids = (const int*)d_in[3];
    float* out = (float*)d_out;

    const size_t pp_bytes   = (size_t)NB * NI * NI * sizeof(unsigned short); // 32 MiB
    const size_t counts_off = pp_bytes;
    const size_t list_off   = counts_off + (size_t)STK * sizeof(int);
    const size_t sid16_off  = list_off + (size_t)STK * CAP * sizeof(int);
    const size_t scale_off  = sid16_off + (size_t)NB * NI * sizeof(unsigned short);
    const size_t need       = scale_off + (size_t)NB * NI * sizeof(float);

    if (ws_size >= need) {
        unsigned short* Pp    = (unsigned short*)d_ws;
        int* counts           = (int*)((char*)d_ws + counts_off);
        int* list             = (int*)((char*)d_ws + list_off);
        unsigned short* sid16 = (unsigned short*)((char*)d_ws + sid16_off);
        float* scale          = (float*)((char*)d_ws + scale_off);
        hipMemsetAsync(counts, 0, (size_t)STK * sizeof(int), stream);
        pass1_att<<<dim3(NB, NI / 64), T1, 0, stream>>>(prices, emb_table, stock_ids,
                                                        Pp, counts, list, sid16, scale);
        pass2_beta<<<STK, T2, 0, stream>>>(prices, beta, sid16, counts, list,
                                           Pp, scale, out);
    } else {
        dim3 grid(NB, NI / TILE_I);
        stock_factor_fallback<<<grid, FB_THREADS, 0, stream>>>(
            prices, emb_table, beta, stock_ids, out);
    }
}